// Round 1
// baseline (390.829 us; speedup 1.0000x reference)
//
#include <hip/hip_runtime.h>

// AttentionActorCritic fused forward, MI355X (gfx950).
// Round 1: fused megakernel. 1 block = 32 samples, 512 threads (8 waves).
// All GEMM-shaped ops via mfma_f32_16x16x32_bf16; attention/LN/heads on VALU fp32.
// Prep kernel converts fp32 weights -> bf16 into d_ws.

typedef __bf16 bhalf;
typedef __bf16 bhalf8 __attribute__((ext_vector_type(8)));
typedef float f32x4 __attribute__((ext_vector_type(4)));

#define DEV static __device__ __forceinline__

DEV f32x4 mfma16(bhalf8 a, bhalf8 b, f32x4 c) {
  return __builtin_amdgcn_mfma_f32_16x16x32_bf16(a, b, c, 0, 0, 0);
}

// ---------------- pointer bundle ----------------
struct Ptrs {
  const float* state;
  // power branch fp32 params
  const float *p_in_w, *p_in_b, *p_qkv_b, *p_o_b, *p_g1, *p_b1, *p_ff1_b, *p_ff2_b, *p_g2, *p_b2, *p_out_b;
  // sword branch fp32 params
  const float *s_in_w, *s_in_b, *s_qkv_b, *s_o_b, *s_g1, *s_b1, *s_ff1_b, *s_ff2_b, *s_g2, *s_b2, *s_out_b;
  const float *e_w, *e_b, *d1_b, *d2_b, *pi_w, *pi_b, *v_w, *v_b;
  // bf16 weights (in d_ws)
  const bhalf *w_qkv, *w_o, *w_ff1, *w_ff2, *w_out;       // power
  const bhalf *w_qkv2, *w_o2, *w_ff12, *w_ff22, *w_out2;  // sword
  const bhalf *w_d1, *w_d2;
  float* out;
};

// ---------------- prep: fp32 -> bf16 weight conversion ----------------
struct PrepArgs {
  const float* src[12];
  int len[12];
  bhalf* dst;
};

__global__ void prep_bf16(PrepArgs a) {
  int idx = blockIdx.x * blockDim.x + threadIdx.x;
  int off = 0;
#pragma unroll
  for (int i = 0; i < 12; ++i) {
    int n = a.len[i];
    if (idx >= off && idx < off + n) a.dst[idx] = (bhalf)a.src[i][idx - off];
    off += n;
  }
}

// ---------------- encoder layer (post-norm transformer) ----------------
// rows are laid out [token][sample]: row = t*32 + s, 32 samples per block.
// xbuf: [T*32][40] bf16 (stride 40 elems = 80B, 16B-aligned rows)
// qkvbuf: [T*32][104] bf16 ; obuf: [T*32][40] bf16 ; tmpf: [T*32][36] f32
template <int T>
DEV void encoder(int tid, int wave, int lane,
                 bhalf* xbuf, bhalf* qkvbuf, bhalf* obuf, float* tmpf,
                 const bhalf* w_qkv, const bhalf* w_o, const bhalf* w_ff1, const bhalf* w_ff2,
                 const float* qkv_b, const float* o_b, const float* g1, const float* b1,
                 const float* ff1_b, const float* ff2_b, const float* g2, const float* b2) {
  const int ROWS = T * 32;
  const int MT = ROWS / 16;
  const int l15 = lane & 15, lq = lane >> 4;

  // ---- QKV projection: [ROWS,32] x [32,96] ----
  for (int f = wave; f < MT * 6; f += 8) {
    int m = f / 6, n = f - m * 6;
    bhalf8 a = *(const bhalf8*)&xbuf[(m * 16 + l15) * 40 + lq * 8];
    bhalf8 b = *(const bhalf8*)&w_qkv[(n * 16 + l15) * 32 + lq * 8];
    f32x4 c = {0.f, 0.f, 0.f, 0.f};
    c = mfma16(a, b, c);
    int col = n * 16 + l15;
    float bias = qkv_b[col];
#pragma unroll
    for (int j = 0; j < 4; ++j)
      qkvbuf[(m * 16 + lq * 4 + j) * 104 + col] = (bhalf)(c[j] + bias);
  }
  __syncthreads();

  // ---- attention (per sample, per head, fp32 on VALU) ----
  {
    const int PARTS = (T + 1) / 2;  // token-chunks of 2
    if (tid < 32 * 4 * PARTS) {
      int s = tid / (4 * PARTS);
      int rem = tid - s * (4 * PARTS);
      int h = rem / PARTS, part = rem - h * PARTS;
      for (int a = part * 2; a < T && a < part * 2 + 2; ++a) {
        float q[8];
#pragma unroll
        for (int i = 0; i < 8; ++i) q[i] = (float)qkvbuf[(a * 32 + s) * 104 + h * 8 + i];
        float sc[T];
        float mx = -1e30f;
#pragma unroll
        for (int b = 0; b < T; ++b) {
          float d = 0.f;
#pragma unroll
          for (int i = 0; i < 8; ++i) d += q[i] * (float)qkvbuf[(b * 32 + s) * 104 + 32 + h * 8 + i];
          d *= 0.35355339059327378f;  // 1/sqrt(8)
          sc[b] = d;
          mx = fmaxf(mx, d);
        }
        float sum = 0.f;
#pragma unroll
        for (int b = 0; b < T; ++b) { sc[b] = __expf(sc[b] - mx); sum += sc[b]; }
        float inv = 1.f / sum;
        float o[8] = {0.f, 0.f, 0.f, 0.f, 0.f, 0.f, 0.f, 0.f};
#pragma unroll
        for (int b = 0; b < T; ++b) {
          float w = sc[b] * inv;
#pragma unroll
          for (int i = 0; i < 8; ++i) o[i] += w * (float)qkvbuf[(b * 32 + s) * 104 + 64 + h * 8 + i];
        }
#pragma unroll
        for (int i = 0; i < 8; ++i) obuf[(a * 32 + s) * 40 + h * 8 + i] = (bhalf)o[i];
      }
    }
  }
  __syncthreads();

  // ---- o-projection + residual -> tmpf (f32) ----
  for (int f = wave; f < MT * 2; f += 8) {
    int m = f >> 1, n = f & 1;
    bhalf8 a = *(const bhalf8*)&obuf[(m * 16 + l15) * 40 + lq * 8];
    bhalf8 b = *(const bhalf8*)&w_o[(n * 16 + l15) * 32 + lq * 8];
    f32x4 c = {0.f, 0.f, 0.f, 0.f};
    c = mfma16(a, b, c);
    int col = n * 16 + l15;
    float bias = o_b[col];
#pragma unroll
    for (int j = 0; j < 4; ++j) {
      int row = m * 16 + lq * 4 + j;
      tmpf[row * 36 + col] = c[j] + bias + (float)xbuf[row * 40 + col];
    }
  }
  __syncthreads();

  // ---- LN1 -> xbuf ----
  if (tid < ROWS) {
    float xv[32], sum = 0.f, ss = 0.f;
#pragma unroll
    for (int e = 0; e < 32; ++e) { float x = tmpf[tid * 36 + e]; xv[e] = x; sum += x; ss += x * x; }
    float mu = sum * 0.03125f;
    float var = ss * 0.03125f - mu * mu;
    float rs = rsqrtf(var + 1e-5f);
#pragma unroll
    for (int e = 0; e < 32; ++e)
      xbuf[tid * 40 + e] = (bhalf)((xv[e] - mu) * rs * g1[e] + b1[e]);
  }
  __syncthreads();

  // ---- FF1 + relu -> obuf ----
  for (int f = wave; f < MT * 2; f += 8) {
    int m = f >> 1, n = f & 1;
    bhalf8 a = *(const bhalf8*)&xbuf[(m * 16 + l15) * 40 + lq * 8];
    bhalf8 b = *(const bhalf8*)&w_ff1[(n * 16 + l15) * 32 + lq * 8];
    f32x4 c = {0.f, 0.f, 0.f, 0.f};
    c = mfma16(a, b, c);
    int col = n * 16 + l15;
    float bias = ff1_b[col];
#pragma unroll
    for (int j = 0; j < 4; ++j)
      obuf[(m * 16 + lq * 4 + j) * 40 + col] = (bhalf)fmaxf(c[j] + bias, 0.f);
  }
  __syncthreads();

  // ---- FF2 + residual -> tmpf ----
  for (int f = wave; f < MT * 2; f += 8) {
    int m = f >> 1, n = f & 1;
    bhalf8 a = *(const bhalf8*)&obuf[(m * 16 + l15) * 40 + lq * 8];
    bhalf8 b = *(const bhalf8*)&w_ff2[(n * 16 + l15) * 32 + lq * 8];
    f32x4 c = {0.f, 0.f, 0.f, 0.f};
    c = mfma16(a, b, c);
    int col = n * 16 + l15;
    float bias = ff2_b[col];
#pragma unroll
    for (int j = 0; j < 4; ++j) {
      int row = m * 16 + lq * 4 + j;
      tmpf[row * 36 + col] = c[j] + bias + (float)xbuf[row * 40 + col];
    }
  }
  __syncthreads();

  // ---- LN2 -> xbuf ----
  if (tid < ROWS) {
    float xv[32], sum = 0.f, ss = 0.f;
#pragma unroll
    for (int e = 0; e < 32; ++e) { float x = tmpf[tid * 36 + e]; xv[e] = x; sum += x; ss += x * x; }
    float mu = sum * 0.03125f;
    float var = ss * 0.03125f - mu * mu;
    float rs = rsqrtf(var + 1e-5f);
#pragma unroll
    for (int e = 0; e < 32; ++e)
      xbuf[tid * 40 + e] = (bhalf)((xv[e] - mu) * rs * g2[e] + b2[e]);
  }
  __syncthreads();
}

// ---- final per-branch embed: relu([32, T*32] x [T*32, 128]) -> xcat cols [cofs, cofs+128) ----
template <int T>
DEV void out_gemm(int wave, int lane, const bhalf* xbuf, const bhalf* w, const float* bias,
                  bhalf* xcat, int cofs) {
  const int l15 = lane & 15, lq = lane >> 4;
  for (int f = wave; f < 16; f += 8) {
    int m = f >> 3, n = f & 7;
    f32x4 c = {0.f, 0.f, 0.f, 0.f};
#pragma unroll
    for (int t = 0; t < T; ++t) {
      bhalf8 a = *(const bhalf8*)&xbuf[(t * 32 + m * 16 + l15) * 40 + lq * 8];
      bhalf8 b = *(const bhalf8*)&w[(n * 16 + l15) * (T * 32) + t * 32 + lq * 8];
      c = mfma16(a, b, c);
    }
    int col = n * 16 + l15;
    float bs = bias[col];
#pragma unroll
    for (int j = 0; j < 4; ++j) {
      int s = m * 16 + lq * 4 + j;
      xcat[s * 392 + cofs + col] = (bhalf)fmaxf(c[j] + bs, 0.f);
    }
  }
}

// ---------------- main fused kernel ----------------
__launch_bounds__(512)
__global__ void aac_main(Ptrs P) {
  // static LDS, 123904 B total
  __shared__ __align__(16) float s_state[32 * 32];     // [32 samples][32 (30 used)]
  __shared__ __align__(16) bhalf s_xp[224 * 40];       // power activations [t*32+s][32]
  __shared__ __align__(16) bhalf s_xs[64 * 40];        // sword activations
  __shared__ __align__(16) bhalf s_qkv[224 * 104];     // qkv scratch; rows 64+ reused as xcat
  __shared__ __align__(16) bhalf s_o[224 * 40];        // attention-out / ff1 scratch; reused as h1
  __shared__ __align__(16) float s_tmpf[224 * 36];     // f32 residual scratch; reused as h2

  bhalf* xcat = s_qkv + 64 * 104;  // [32][392] bf16  (p_emb | s_emb | st_emb)
  bhalf* h1 = s_o;                 // [32][136] bf16
  float* h2 = s_tmpf;              // [32][132] f32

  const int tid = threadIdx.x;
  const int wave = tid >> 6, lane = tid & 63;
  const int l15 = lane & 15, lq = lane >> 4;
  const int s0 = blockIdx.x * 32;

  // S0: stage state tile
  for (int i = tid; i < 32 * 30; i += 512) {
    int s = i / 30, c = i - s * 30;
    s_state[s * 32 + c] = P.state[(size_t)(s0 + s) * 30 + c];
  }
  __syncthreads();

  // S1: input linears (fp32 VALU, K=2 / K=4)
  for (int i = tid; i < 224 * 32; i += 512) {
    int row = i >> 5, e = i & 31;
    int t = row >> 5, s = row & 31;
    float v = P.p_in_b[e] + P.p_in_w[e * 2] * s_state[s * 32 + t * 2]
                          + P.p_in_w[e * 2 + 1] * s_state[s * 32 + t * 2 + 1];
    s_xp[row * 40 + e] = (bhalf)v;
  }
  for (int i = tid; i < 64 * 32; i += 512) {
    int row = i >> 5, e = i & 31;
    int t = row >> 5, s = row & 31;
    float v = P.s_in_b[e];
#pragma unroll
    for (int j = 0; j < 4; ++j) v += P.s_in_w[e * 4 + j] * s_state[s * 32 + 14 + t * 4 + j];
    s_xs[row * 40 + e] = (bhalf)v;
  }
  __syncthreads();

  // power encoder + embed
  encoder<7>(tid, wave, lane, s_xp, s_qkv, s_o, s_tmpf,
             P.w_qkv, P.w_o, P.w_ff1, P.w_ff2,
             P.p_qkv_b, P.p_o_b, P.p_g1, P.p_b1, P.p_ff1_b, P.p_ff2_b, P.p_g2, P.p_b2);
  out_gemm<7>(wave, lane, s_xp, P.w_out, P.p_out_b, xcat, 0);
  __syncthreads();

  // sword encoder + embed (uses only rows 0..63 of scratch; xcat lives at rows 64+)
  encoder<2>(tid, wave, lane, s_xs, s_qkv, s_o, s_tmpf,
             P.w_qkv2, P.w_o2, P.w_ff12, P.w_ff22,
             P.s_qkv_b, P.s_o_b, P.s_g1, P.s_b1, P.s_ff1_b, P.s_ff2_b, P.s_g2, P.s_b2);
  out_gemm<2>(wave, lane, s_xs, P.w_out2, P.s_out_b, xcat, 128);

  // state embed -> xcat cols 256..383
  for (int i = tid; i < 32 * 128; i += 512) {
    int s = i >> 7, col = i & 127;
    float v = P.e_b[col];
#pragma unroll
    for (int j = 0; j < 8; ++j) v += P.e_w[col * 8 + j] * s_state[s * 32 + 22 + j];
    xcat[s * 392 + 256 + col] = (bhalf)fmaxf(v, 0.f);
  }
  __syncthreads();

  // d1: [32,384] x [384,128] + relu -> h1
  for (int f = wave; f < 16; f += 8) {
    int m = f >> 3, n = f & 7;
    f32x4 c = {0.f, 0.f, 0.f, 0.f};
#pragma unroll
    for (int ks = 0; ks < 12; ++ks) {
      bhalf8 a = *(const bhalf8*)&xcat[(m * 16 + l15) * 392 + ks * 32 + lq * 8];
      bhalf8 b = *(const bhalf8*)&P.w_d1[(n * 16 + l15) * 384 + ks * 32 + lq * 8];
      c = mfma16(a, b, c);
    }
    int col = n * 16 + l15;
    float bs = P.d1_b[col];
#pragma unroll
    for (int j = 0; j < 4; ++j)
      h1[(m * 16 + lq * 4 + j) * 136 + col] = (bhalf)fmaxf(c[j] + bs, 0.f);
  }
  __syncthreads();

  // d2: [32,128] x [128,128] + relu -> h2 (f32)
  for (int f = wave; f < 16; f += 8) {
    int m = f >> 3, n = f & 7;
    f32x4 c = {0.f, 0.f, 0.f, 0.f};
#pragma unroll
    for (int ks = 0; ks < 4; ++ks) {
      bhalf8 a = *(const bhalf8*)&h1[(m * 16 + l15) * 136 + ks * 32 + lq * 8];
      bhalf8 b = *(const bhalf8*)&P.w_d2[(n * 16 + l15) * 128 + ks * 32 + lq * 8];
      c = mfma16(a, b, c);
    }
    int col = n * 16 + l15;
    float bs = P.d2_b[col];
#pragma unroll
    for (int j = 0; j < 4; ++j)
      h2[(m * 16 + lq * 4 + j) * 132 + col] = fmaxf(c[j] + bs, 0.f);
  }
  __syncthreads();

  // heads: 8 threads per sample (7 pi logits + 1 v), softmax via 8-lane shuffle
  if (tid < 256) {
    int s = tid >> 3, o = tid & 7;
    const float* wrow = (o < 7) ? (P.pi_w + o * 128) : P.v_w;
    float acc = (o < 7) ? P.pi_b[o] : P.v_b[0];
    for (int k = 0; k < 128; ++k) acc += wrow[k] * h2[s * 132 + k];
    float x = (o < 7) ? acc : -1e30f;
#pragma unroll
    for (int m = 1; m < 8; m <<= 1) x = fmaxf(x, __shfl_xor(x, m));
    float e = (o < 7) ? __expf(acc - x) : 0.f;
    float ssum = e;
#pragma unroll
    for (int m = 1; m < 8; m <<= 1) ssum += __shfl_xor(ssum, m);
    if (o < 7) P.out[(size_t)(s0 + s) * 7 + o] = e / ssum;
    else       P.out[917504 + s0 + s] = acc;  // 131072*7
  }
}

// ---------------- launch ----------------
extern "C" void kernel_launch(void* const* d_in, const int* in_sizes, int n_in,
                              void* d_out, int out_size, void* d_ws, size_t ws_size,
                              hipStream_t stream) {
  (void)in_sizes; (void)n_in; (void)out_size; (void)ws_size;
  const float* const* in = (const float* const*)d_in;
  bhalf* wbf = (bhalf*)d_ws;

  // weight -> bf16 prep (ws layout in elements)
  PrepArgs pa;
  const int srcIdx[12] = {3, 5, 9, 11, 15, 19, 21, 25, 27, 31, 35, 37};
  const int lens[12] = {3072, 1024, 1024, 1024, 28672, 3072, 1024, 1024, 1024, 8192, 49152, 16384};
  for (int i = 0; i < 12; ++i) { pa.src[i] = in[srcIdx[i]]; pa.len[i] = lens[i]; }
  pa.dst = wbf;
  hipLaunchKernelGGL(prep_bf16, dim3(448), dim3(256), 0, stream, pa);  // 448*256 = 114688 elems

  Ptrs P;
  P.state = in[0];
  P.p_in_w = in[1];  P.p_in_b = in[2];  P.p_qkv_b = in[4];  P.p_o_b = in[6];
  P.p_g1 = in[7];    P.p_b1 = in[8];    P.p_ff1_b = in[10]; P.p_ff2_b = in[12];
  P.p_g2 = in[13];   P.p_b2 = in[14];   P.p_out_b = in[16];
  P.s_in_w = in[17]; P.s_in_b = in[18]; P.s_qkv_b = in[20]; P.s_o_b = in[22];
  P.s_g1 = in[23];   P.s_b1 = in[24];   P.s_ff1_b = in[26]; P.s_ff2_b = in[28];
  P.s_g2 = in[29];   P.s_b2 = in[30];   P.s_out_b = in[32];
  P.e_w = in[33];    P.e_b = in[34];    P.d1_b = in[36];    P.d2_b = in[38];
  P.pi_w = in[39];   P.pi_b = in[40];   P.v_w = in[41];     P.v_b = in[42];
  P.w_qkv = wbf;             P.w_o = wbf + 3072;    P.w_ff1 = wbf + 4096;
  P.w_ff2 = wbf + 5120;      P.w_out = wbf + 6144;
  P.w_qkv2 = wbf + 34816;    P.w_o2 = wbf + 37888;  P.w_ff12 = wbf + 38912;
  P.w_ff22 = wbf + 39936;    P.w_out2 = wbf + 40960;
  P.w_d1 = wbf + 49152;      P.w_d2 = wbf + 98304;
  P.out = (float*)d_out;

  hipLaunchKernelGGL(aac_main, dim3(4096), dim3(512), 0, stream, P);  // 131072/32 blocks
}

// Round 2
// 345.272 us; speedup vs baseline: 1.1319x; 1.1319x over previous
//
#include <hip/hip_runtime.h>

// AttentionActorCritic fused forward, MI355X (gfx950).
// Round 2: 16 samples/block, 80000B LDS -> 2 blocks/CU (4 waves/SIMD).
// Power+sword branches fused into shared phases (144-row tile space).
// Vectorized attention (b128 q/k/v reads), vectorized LN (f32x4), vectorized
// heads (LDS-staged pi/v weights). MFMA operands swapped (A=weight, B=act)
// so epilogue stores are packed b64/b128.

typedef __bf16 bhalf;
typedef __bf16 bhalf4 __attribute__((ext_vector_type(4)));
typedef __bf16 bhalf8 __attribute__((ext_vector_type(8)));
typedef float f32x4 __attribute__((ext_vector_type(4)));

#define DEV static __device__ __forceinline__

DEV f32x4 mfma16(bhalf8 a, bhalf8 b, f32x4 c) {
  return __builtin_amdgcn_mfma_f32_16x16x32_bf16(a, b, c, 0, 0, 0);
}

// ---------------- pointer bundle ----------------
struct Ptrs {
  const float* state;
  const float *p_in_w, *p_in_b, *p_qkv_b, *p_o_b, *p_g1, *p_b1, *p_ff1_b, *p_ff2_b, *p_g2, *p_b2, *p_out_b;
  const float *s_in_w, *s_in_b, *s_qkv_b, *s_o_b, *s_g1, *s_b1, *s_ff1_b, *s_ff2_b, *s_g2, *s_b2, *s_out_b;
  const float *e_w, *e_b, *d1_b, *d2_b, *pi_w, *pi_b, *v_w, *v_b;
  const bhalf *w_qkv, *w_o, *w_ff1, *w_ff2, *w_out;       // power
  const bhalf *w_qkv2, *w_o2, *w_ff12, *w_ff22, *w_out2;  // sword
  const bhalf *w_d1, *w_d2;
  float* out;
};

// ---------------- prep: fp32 -> bf16 weight conversion ----------------
struct PrepArgs {
  const float* src[12];
  int len[12];
  bhalf* dst;
};

__global__ void prep_bf16(PrepArgs a) {
  int idx = blockIdx.x * blockDim.x + threadIdx.x;
  int off = 0;
#pragma unroll
  for (int i = 0; i < 12; ++i) {
    int n = a.len[i];
    if (idx >= off && idx < off + n) a.dst[idx] = (bhalf)a.src[i][idx - off];
    off += n;
  }
}

// ---------------- attention: one (token a, sample s, head h) ----------------
template <int T>
DEV void attn_head(const bhalf* qkv, bhalf* obuf, int rowbase, int a, int s, int h) {
  const bhalf8 qv = *(const bhalf8*)&qkv[(rowbase + a * 16 + s) * 104 + h * 8];
  float q[8];
#pragma unroll
  for (int i = 0; i < 8; ++i) q[i] = (float)qv[i];
  float sc[T];
  float mx = -1e30f;
#pragma unroll
  for (int b = 0; b < T; ++b) {
    bhalf8 kv = *(const bhalf8*)&qkv[(rowbase + b * 16 + s) * 104 + 32 + h * 8];
    float d = 0.f;
#pragma unroll
    for (int i = 0; i < 8; ++i) d += q[i] * (float)kv[i];
    d *= 0.35355339059327378f;  // 1/sqrt(8)
    sc[b] = d;
    mx = fmaxf(mx, d);
  }
  float sum = 0.f;
#pragma unroll
  for (int b = 0; b < T; ++b) { sc[b] = __expf(sc[b] - mx); sum += sc[b]; }
  float inv = 1.f / sum;
  float o[8] = {0.f, 0.f, 0.f, 0.f, 0.f, 0.f, 0.f, 0.f};
#pragma unroll
  for (int b = 0; b < T; ++b) {
    bhalf8 vv = *(const bhalf8*)&qkv[(rowbase + b * 16 + s) * 104 + 64 + h * 8];
    float w = sc[b] * inv;
#pragma unroll
    for (int i = 0; i < 8; ++i) o[i] += w * (float)vv[i];
  }
  bhalf8 ov;
#pragma unroll
  for (int i = 0; i < 8; ++i) ov[i] = (bhalf)o[i];
  *(bhalf8*)&obuf[(rowbase + a * 16 + s) * 40 + h * 8] = ov;
}

// ---------------- LayerNorm pass: tmpf(f32) -> s_x(bf16), 2 threads/row ----------------
DEV void ln_pass(int tid, const float* tmpf, bhalf* xb,
                 const float* gp, const float* bp, const float* gs, const float* bs) {
  if (tid < 288) {
    int row = tid >> 1, half = tid & 1;
    const float* src = &tmpf[row * 36 + half * 16];
    f32x4 v0 = *(const f32x4*)(src);
    f32x4 v1 = *(const f32x4*)(src + 4);
    f32x4 v2 = *(const f32x4*)(src + 8);
    f32x4 v3 = *(const f32x4*)(src + 12);
    float sum = 0.f, ss = 0.f;
#pragma unroll
    for (int i = 0; i < 4; ++i) {
      sum += v0[i] + v1[i] + v2[i] + v3[i];
      ss += v0[i] * v0[i] + v1[i] * v1[i] + v2[i] * v2[i] + v3[i] * v3[i];
    }
    sum += __shfl_xor(sum, 1);
    ss += __shfl_xor(ss, 1);
    float mu = sum * 0.03125f;
    float var = ss * 0.03125f - mu * mu;
    float rs = rsqrtf(var + 1e-5f);
    const float* g = (row < 112) ? gp : gs;
    const float* b = (row < 112) ? bp : bs;
    f32x4 g0 = *(const f32x4*)&g[half * 16];
    f32x4 g1 = *(const f32x4*)&g[half * 16 + 4];
    f32x4 g2 = *(const f32x4*)&g[half * 16 + 8];
    f32x4 g3 = *(const f32x4*)&g[half * 16 + 12];
    f32x4 b0 = *(const f32x4*)&b[half * 16];
    f32x4 b1 = *(const f32x4*)&b[half * 16 + 4];
    f32x4 b2 = *(const f32x4*)&b[half * 16 + 8];
    f32x4 b3 = *(const f32x4*)&b[half * 16 + 12];
    bhalf8 o0, o1;
#pragma unroll
    for (int i = 0; i < 4; ++i) {
      o0[i] = (bhalf)((v0[i] - mu) * rs * g0[i] + b0[i]);
      o0[i + 4] = (bhalf)((v1[i] - mu) * rs * g1[i] + b1[i]);
      o1[i] = (bhalf)((v2[i] - mu) * rs * g2[i] + b2[i]);
      o1[i + 4] = (bhalf)((v3[i] - mu) * rs * g3[i] + b3[i]);
    }
    *(bhalf8*)&xb[row * 40 + half * 16] = o0;
    *(bhalf8*)&xb[row * 40 + half * 16 + 8] = o1;
  }
}

// ---------------- main fused kernel ----------------
__launch_bounds__(512, 4)
__global__ void aac_main(Ptrs P) {
  // 80000 B total LDS -> 2 blocks/CU
  __shared__ __align__(16) float s_state[16 * 32];   // 2048 B
  __shared__ __align__(16) float s_pw[8 * 132];      // 4224 B: pi_w rows 0-6, v_w row 7
  __shared__ __align__(16) bhalf s_x[144 * 40];      // 11520 B: activations (power rows 0-111, sword 112-143)
  __shared__ __align__(16) bhalf s_qkv[144 * 104];   // 29952 B: qkv; later aliased as xcat [16][400]
  __shared__ __align__(16) bhalf s_o[144 * 40];      // 11520 B: attn-out / ff1; later h1 [16][136]
  __shared__ __align__(16) float s_tmpf[144 * 36];   // 20736 B: f32 residual; later h2 [16][132]

  bhalf* xcat = s_qkv;  // [16][400]
  bhalf* h1 = s_o;      // [16][136]
  float* h2 = s_tmpf;   // [16][132]

  const int tid = threadIdx.x;
  const int wave = tid >> 6, lane = tid & 63;
  const int l15 = lane & 15, lq = lane >> 4;
  const int s0 = blockIdx.x * 16;

  // ---- stage state + pi/v weights ----
  for (int i = tid; i < 16 * 30; i += 512) {
    int s = i / 30, c = i - s * 30;
    s_state[s * 32 + c] = P.state[(size_t)(s0 + s) * 30 + c];
  }
  for (int i = tid; i < 1024; i += 512) {
    int r = i >> 7, c = i & 127;
    s_pw[r * 132 + c] = (r < 7) ? P.pi_w[r * 128 + c] : P.v_w[c];
  }
  __syncthreads();

  // ---- input linears (K=2 power, K=4 sword) ----
  for (int i = tid; i < 112 * 32; i += 512) {
    int row = i >> 5, e = i & 31;
    int t = row >> 4, s = row & 15;
    float v = P.p_in_b[e] + P.p_in_w[e * 2] * s_state[s * 32 + t * 2]
                          + P.p_in_w[e * 2 + 1] * s_state[s * 32 + t * 2 + 1];
    s_x[row * 40 + e] = (bhalf)v;
  }
  for (int i = tid; i < 32 * 32; i += 512) {
    int row = i >> 5, e = i & 31;
    int t = row >> 4, s = row & 15;
    float v = P.s_in_b[e];
#pragma unroll
    for (int j = 0; j < 4; ++j) v += P.s_in_w[e * 4 + j] * s_state[s * 32 + 14 + t * 4 + j];
    s_x[(112 + row) * 40 + e] = (bhalf)v;
  }
  __syncthreads();

  // ---- QKV: 9 M-tiles x 6 N-tiles, both branches ----
  for (int f = wave; f < 54; f += 8) {
    int mt = f / 6, n = f - mt * 6;
    bool sw = mt >= 7;
    const bhalf* wq = sw ? P.w_qkv2 : P.w_qkv;
    const float* qb = sw ? P.s_qkv_b : P.p_qkv_b;
    bhalf8 a = *(const bhalf8*)&wq[(n * 16 + l15) * 32 + lq * 8];
    bhalf8 b = *(const bhalf8*)&s_x[(mt * 16 + l15) * 40 + lq * 8];
    f32x4 c = {0.f, 0.f, 0.f, 0.f};
    c = mfma16(a, b, c);
    int arow = mt * 16 + l15, oc0 = n * 16 + lq * 4;
    bhalf4 o;
#pragma unroll
    for (int j = 0; j < 4; ++j) o[j] = (bhalf)(c[j] + qb[oc0 + j]);
    *(bhalf4*)&s_qkv[arow * 104 + oc0] = o;
  }
  __syncthreads();

  // ---- attention: power waves 0-6 (1 token each), sword wave 7 ----
  if (tid < 448) {
    int a = tid >> 6;
    int idx = tid & 63, s = idx >> 2, h = idx & 3;
    attn_head<7>(s_qkv, s_o, 0, a, s, h);
  } else {
    int idx = tid - 448, s = idx >> 2, h = idx & 3;
    attn_head<2>(s_qkv, s_o, 112, 0, s, h);
    attn_head<2>(s_qkv, s_o, 112, 1, s, h);
  }
  __syncthreads();

  // ---- o-projection + residual -> tmpf ----
  for (int f = wave; f < 18; f += 8) {
    int mt = f >> 1, n = f & 1;
    bool sw = mt >= 7;
    const bhalf* wo = sw ? P.w_o2 : P.w_o;
    const float* ob = sw ? P.s_o_b : P.p_o_b;
    bhalf8 a = *(const bhalf8*)&wo[(n * 16 + l15) * 32 + lq * 8];
    bhalf8 b = *(const bhalf8*)&s_o[(mt * 16 + l15) * 40 + lq * 8];
    f32x4 c = {0.f, 0.f, 0.f, 0.f};
    c = mfma16(a, b, c);
    int arow = mt * 16 + l15, oc0 = n * 16 + lq * 4;
    bhalf4 res = *(const bhalf4*)&s_x[arow * 40 + oc0];
    f32x4 o;
#pragma unroll
    for (int j = 0; j < 4; ++j) o[j] = c[j] + ob[oc0 + j] + (float)res[j];
    *(f32x4*)&s_tmpf[arow * 36 + oc0] = o;
  }
  __syncthreads();

  // ---- LN1 ----
  ln_pass(tid, s_tmpf, s_x, P.p_g1, P.p_b1, P.s_g1, P.s_b1);
  __syncthreads();

  // ---- FF1 + relu -> s_o ----
  for (int f = wave; f < 18; f += 8) {
    int mt = f >> 1, n = f & 1;
    bool sw = mt >= 7;
    const bhalf* wf = sw ? P.w_ff12 : P.w_ff1;
    const float* fb = sw ? P.s_ff1_b : P.p_ff1_b;
    bhalf8 a = *(const bhalf8*)&wf[(n * 16 + l15) * 32 + lq * 8];
    bhalf8 b = *(const bhalf8*)&s_x[(mt * 16 + l15) * 40 + lq * 8];
    f32x4 c = {0.f, 0.f, 0.f, 0.f};
    c = mfma16(a, b, c);
    int arow = mt * 16 + l15, oc0 = n * 16 + lq * 4;
    bhalf4 o;
#pragma unroll
    for (int j = 0; j < 4; ++j) o[j] = (bhalf)fmaxf(c[j] + fb[oc0 + j], 0.f);
    *(bhalf4*)&s_o[arow * 40 + oc0] = o;
  }
  __syncthreads();

  // ---- FF2 + residual -> tmpf ----
  for (int f = wave; f < 18; f += 8) {
    int mt = f >> 1, n = f & 1;
    bool sw = mt >= 7;
    const bhalf* wf = sw ? P.w_ff22 : P.w_ff2;
    const float* fb = sw ? P.s_ff2_b : P.p_ff2_b;
    bhalf8 a = *(const bhalf8*)&wf[(n * 16 + l15) * 32 + lq * 8];
    bhalf8 b = *(const bhalf8*)&s_o[(mt * 16 + l15) * 40 + lq * 8];
    f32x4 c = {0.f, 0.f, 0.f, 0.f};
    c = mfma16(a, b, c);
    int arow = mt * 16 + l15, oc0 = n * 16 + lq * 4;
    bhalf4 res = *(const bhalf4*)&s_x[arow * 40 + oc0];
    f32x4 o;
#pragma unroll
    for (int j = 0; j < 4; ++j) o[j] = c[j] + fb[oc0 + j] + (float)res[j];
    *(f32x4*)&s_tmpf[arow * 36 + oc0] = o;
  }
  __syncthreads();

  // ---- LN2 ----
  ln_pass(tid, s_tmpf, s_x, P.p_g2, P.p_b2, P.s_g2, P.s_b2);
  __syncthreads();

  // ---- out_gemm (both branches) + st_emb -> xcat ----
  for (int f = wave; f < 16; f += 8) {
    int br = f >> 3, n = f & 7;
    int T = br ? 2 : 7, rowbase = br ? 112 : 0;
    const bhalf* w = br ? P.w_out2 : P.w_out;
    int wst = br ? 64 : 224;
    const float* bb = br ? P.s_out_b : P.p_out_b;
    f32x4 c = {0.f, 0.f, 0.f, 0.f};
    for (int t = 0; t < T; ++t) {
      bhalf8 a = *(const bhalf8*)&w[(n * 16 + l15) * wst + t * 32 + lq * 8];
      bhalf8 b = *(const bhalf8*)&s_x[(rowbase + t * 16 + l15) * 40 + lq * 8];
      c = mfma16(a, b, c);
    }
    int samp = l15, oc = n * 16 + lq * 4;
    bhalf4 o;
#pragma unroll
    for (int j = 0; j < 4; ++j) o[j] = (bhalf)fmaxf(c[j] + bb[oc + j], 0.f);
    *(bhalf4*)&xcat[samp * 400 + br * 128 + oc] = o;
  }
  for (int i = tid; i < 16 * 128; i += 512) {
    int s = i >> 7, col = i & 127;
    f32x4 w0 = *(const f32x4*)&P.e_w[col * 8];
    f32x4 w1 = *(const f32x4*)&P.e_w[col * 8 + 4];
    float v = P.e_b[col];
#pragma unroll
    for (int j = 0; j < 4; ++j)
      v += w0[j] * s_state[s * 32 + 22 + j] + w1[j] * s_state[s * 32 + 26 + j];
    xcat[s * 400 + 256 + col] = (bhalf)fmaxf(v, 0.f);
  }
  __syncthreads();

  // ---- d1: [16,384] x [384,128] + relu -> h1 ----
  {
    int n = wave;
    f32x4 c = {0.f, 0.f, 0.f, 0.f};
#pragma unroll
    for (int ks = 0; ks < 12; ++ks) {
      bhalf8 a = *(const bhalf8*)&P.w_d1[(n * 16 + l15) * 384 + ks * 32 + lq * 8];
      bhalf8 b = *(const bhalf8*)&xcat[l15 * 400 + ks * 32 + lq * 8];
      c = mfma16(a, b, c);
    }
    int oc = n * 16 + lq * 4;
    bhalf4 o;
#pragma unroll
    for (int j = 0; j < 4; ++j) o[j] = (bhalf)fmaxf(c[j] + P.d1_b[oc + j], 0.f);
    __syncthreads();  // xcat fully read; also orders h1 alias (h1 written after this point only)
    *(bhalf4*)&h1[l15 * 136 + oc] = o;
  }
  __syncthreads();

  // ---- d2: [16,128] x [128,128] + relu -> h2 (f32) ----
  {
    int n = wave;
    f32x4 c = {0.f, 0.f, 0.f, 0.f};
#pragma unroll
    for (int ks = 0; ks < 4; ++ks) {
      bhalf8 a = *(const bhalf8*)&P.w_d2[(n * 16 + l15) * 128 + ks * 32 + lq * 8];
      bhalf8 b = *(const bhalf8*)&h1[l15 * 136 + ks * 32 + lq * 8];
      c = mfma16(a, b, c);
    }
    int oc = n * 16 + lq * 4;
    f32x4 o;
#pragma unroll
    for (int j = 0; j < 4; ++j) o[j] = fmaxf(c[j] + P.d2_b[oc + j], 0.f);
    *(f32x4*)&h2[l15 * 132 + oc] = o;
  }
  __syncthreads();

  // ---- heads: 8 lanes/sample, pi softmax via 8-lane shuffle, v in f32 ----
  if (tid < 128) {
    int s = tid >> 3, o = tid & 7;
    const float* wrow = &s_pw[o * 132];
    float acc = (o < 7) ? P.pi_b[o] : P.v_b[0];
#pragma unroll
    for (int kq = 0; kq < 32; ++kq) {
      f32x4 wv = *(const f32x4*)&wrow[kq * 4];
      f32x4 hv = *(const f32x4*)&h2[s * 132 + kq * 4];
#pragma unroll
      for (int j = 0; j < 4; ++j) acc += wv[j] * hv[j];
    }
    float x = (o < 7) ? acc : -1e30f;
#pragma unroll
    for (int m = 1; m < 8; m <<= 1) x = fmaxf(x, __shfl_xor(x, m));
    float e = (o < 7) ? __expf(acc - x) : 0.f;
    float ssum = e;
#pragma unroll
    for (int m = 1; m < 8; m <<= 1) ssum += __shfl_xor(ssum, m);
    if (o < 7) P.out[(size_t)(s0 + s) * 7 + o] = e / ssum;
    else       P.out[917504 + s0 + s] = acc;  // 131072*7
  }
}

// ---------------- launch ----------------
extern "C" void kernel_launch(void* const* d_in, const int* in_sizes, int n_in,
                              void* d_out, int out_size, void* d_ws, size_t ws_size,
                              hipStream_t stream) {
  (void)in_sizes; (void)n_in; (void)out_size; (void)ws_size;
  const float* const* in = (const float* const*)d_in;
  bhalf* wbf = (bhalf*)d_ws;

  PrepArgs pa;
  const int srcIdx[12] = {3, 5, 9, 11, 15, 19, 21, 25, 27, 31, 35, 37};
  const int lens[12] = {3072, 1024, 1024, 1024, 28672, 3072, 1024, 1024, 1024, 8192, 49152, 16384};
  for (int i = 0; i < 12; ++i) { pa.src[i] = in[srcIdx[i]]; pa.len[i] = lens[i]; }
  pa.dst = wbf;
  hipLaunchKernelGGL(prep_bf16, dim3(448), dim3(256), 0, stream, pa);

  Ptrs P;
  P.state = in[0];
  P.p_in_w = in[1];  P.p_in_b = in[2];  P.p_qkv_b = in[4];  P.p_o_b = in[6];
  P.p_g1 = in[7];    P.p_b1 = in[8];    P.p_ff1_b = in[10]; P.p_ff2_b = in[12];
  P.p_g2 = in[13];   P.p_b2 = in[14];   P.p_out_b = in[16];
  P.s_in_w = in[17]; P.s_in_b = in[18]; P.s_qkv_b = in[20]; P.s_o_b = in[22];
  P.s_g1 = in[23];   P.s_b1 = in[24];   P.s_ff1_b = in[26]; P.s_ff2_b = in[28];
  P.s_g2 = in[29];   P.s_b2 = in[30];   P.s_out_b = in[32];
  P.e_w = in[33];    P.e_b = in[34];    P.d1_b = in[36];    P.d2_b = in[38];
  P.pi_w = in[39];   P.pi_b = in[40];   P.v_w = in[41];     P.v_b = in[42];
  P.w_qkv = wbf;             P.w_o = wbf + 3072;    P.w_ff1 = wbf + 4096;
  P.w_ff2 = wbf + 5120;      P.w_out = wbf + 6144;
  P.w_qkv2 = wbf + 34816;    P.w_o2 = wbf + 37888;  P.w_ff12 = wbf + 38912;
  P.w_ff22 = wbf + 39936;    P.w_out2 = wbf + 40960;
  P.w_d1 = wbf + 49152;      P.w_d2 = wbf + 98304;
  P.out = (float*)d_out;

  hipLaunchKernelGGL(aac_main, dim3(8192), dim3(512), 0, stream, P);  // 131072/16 blocks
}